// Round 1
// baseline (323.625 us; speedup 1.0000x reference)
//
#include <hip/hip_runtime.h>

// Fully fused: out = wpw · depthwise3x3( bilinear_up(x) )
// One kernel per whole problem; d_ws holds only a 64 KB bf16 copy of wpw.
// Per block: 128 cout x (4 rows x 32 cols) output tile, K-chunked (4 x 64 cin).
//   chunk: stage x pair-words + folded A weights -> BAR -> per-thread dw into
//   double-buffered [px][cin] LDS tile -> BAR -> MFMA (A-frags from global).
#define CIN  256
#define HIN  60
#define WIN  80
#define UPH  120
#define UPW  160
#define COUT 128
#define NPIX (UPH*UPW)   // 19200

typedef __bf16 bf16x2 __attribute__((ext_vector_type(2)));
typedef __bf16 bf16x8 __attribute__((ext_vector_type(8)));
typedef float  floatx4 __attribute__((ext_vector_type(4)));

// ---------------- wpw fp32 -> bf16 [COUT][CIN] (runs once) ----------------
__global__ void wpw_cvt(const float* __restrict__ wpw, __bf16* __restrict__ wpwb)
{
    int i = (blockIdx.x * blockDim.x + threadIdx.x) * 8;
    float4 a = *(const float4*)(wpw + i);
    float4 b = *(const float4*)(wpw + i + 4);
    bf16x8 o = {(__bf16)a.x,(__bf16)a.y,(__bf16)a.z,(__bf16)a.w,
                (__bf16)b.x,(__bf16)b.y,(__bf16)b.z,(__bf16)b.w};
    *(bf16x8*)(wpwb + i) = o;
}

// ---------------- fused kernel ----------------
#define F_NT 512
#define KC   64            // cin per chunk
#define NCK  (CIN/KC)      // 4
#define PXR  5             // input rows staged (covers 4 out rows + interp)
#define PXW  20            // staged pair-word cols (covers 32 out cols + halo)
#define DWS  72            // s_dw row stride in shorts (144B -> 2-way = free)
#define AST  37            // s_A per-channel stride (odd -> conflict-free)

__global__ __launch_bounds__(F_NT, 4) void fused_kernel(
    const float* __restrict__ x,      // [8,256,60,80]
    const float* __restrict__ wdw,    // [256,1,3,3]
    const __bf16* __restrict__ wpwb,  // [128,256] bf16
    float* __restrict__ out)          // [8,128,120,160]
{
    __shared__ bf16x2 s_px[PXR*PXW*64];       // 25.6 KB  [r][c][cl]
    __shared__ __bf16 s_dw[2][128*DWS];       // 36.9 KB  [px][cin] dbuf
    __shared__ float  s_A[64*AST];            // 9.5 KB   [cl][hh*9+dy*3+j]
    __shared__ float  s_rw[36];               // row-interp weights [hh][i][dy]

    const int tid = threadIdx.x;
    const int wt = blockIdx.x, ht = blockIdx.y, b = blockIdx.z;
    const int h0 = ht*4, w0 = wt*32;

    const float HS = 59.0f/121.0f, WS = 79.0f/161.0f;
    const int rbase = (int)((float)h0*HS);
    const int c0 = (int)((float)w0*WS);

    // block-invariant row-interp weights: rw[hh][i][dy]
    if (tid < 36) {
        int hh = tid/9, t = tid - hh*9;
        int i3 = t/3, dy = t - i3*3;
        int ybh = (int)((float)(h0+hh)*HS);
        float hy = (float)(h0+hh+i3)*HS;
        int y0 = (int)hy; float fy = hy - (float)y0;
        int y1 = min(y0+1, HIN-1);
        s_rw[tid] = ((y0-ybh)==dy ? 1.f-fy : 0.f) + ((y1-ybh)==dy ? fy : 0.f);
    }

    // dw-producer decode: thread = (cl in chunk, 8-px col seg, 2-row pair)
    const int cl = tid & 63;
    const int wseg = (tid>>6)&3;
    const int hp = tid>>8;
    const int hh0 = hp*2;
    const int rl0 = (int)((float)(h0+hh0)*HS) - rbase;              // 0..2
    const int dd  = ((int)((float)(h0+hh0+1)*HS) - rbase) - rl0;    // 0 or 1

    float fx[10]; int wi[10];
    #pragma unroll
    for (int j = 0; j < 10; j++) {
        float wx = (float)(w0 + wseg*8 + j) * WS;
        int x0 = (int)wx;
        fx[j] = wx - (float)x0;
        wi[j] = (x0 - c0)*64 + cl;
    }

    // MFMA decode
    const int lane = tid & 63, wave = tid >> 6;
    const int quad = lane >> 4, l16 = lane & 15;
    const int co = (wave & 3)*32, phx = (wave >> 2)*64;

    floatx4 acc[2][4];
    #pragma unroll
    for (int a = 0; a < 2; a++)
        #pragma unroll
        for (int p = 0; p < 4; p++) acc[a][p] = (floatx4){0.f,0.f,0.f,0.f};

    const float* xb = x + (size_t)b * CIN * (HIN*WIN);

    __syncthreads();   // s_rw visible

    for (int ck = 0; ck < NCK; ck++) {
        const int cb = ck * KC;

        // ---- stage x pair-words: 64ch x 5r x 5 quads = 1600 items ----
        #pragma unroll
        for (int k = 0; k < 4; k++) {
            int i = tid + k*F_NT;
            if (i < 1600) {
                int ch = i & 63, rq = i >> 6;     // rq 0..24
                int r = rq/5, q = rq - r*5;
                int gy = min(rbase + r, HIN-1);
                const float* xrow = xb + (size_t)(cb+ch)*(HIN*WIN) + gy*WIN;
                int cq = c0 + q*4;
                int base = (r*PXW + q*4)*64 + ch;
                if (cq + 4 <= WIN-1) {
                    float4 v = *(const float4*)(xrow + cq);
                    float x5 = xrow[cq+4];
                    s_px[base       ] = (bf16x2){(__bf16)v.x,(__bf16)v.y};
                    s_px[base +   64] = (bf16x2){(__bf16)v.y,(__bf16)v.z};
                    s_px[base + 2*64] = (bf16x2){(__bf16)v.z,(__bf16)v.w};
                    s_px[base + 3*64] = (bf16x2){(__bf16)v.w,(__bf16)x5};
                } else {
                    float f[5];
                    #pragma unroll
                    for (int kk = 0; kk < 5; kk++) f[kk] = xrow[min(cq+kk, WIN-1)];
                    #pragma unroll
                    for (int kk = 0; kk < 4; kk++)
                        s_px[base + kk*64] = (bf16x2){(__bf16)f[kk],(__bf16)f[kk+1]};
                }
            }
        }

        // ---- stage folded A: 64ch x 4hh x 9 = 2304 items ----
        #pragma unroll
        for (int k = 0; k < 5; k++) {
            int i = tid + k*F_NT;
            if (i < 2304) {
                int ci = i & 63, t = i >> 6;       // t = hh*9 + dy*3 + j, 0..35
                int hh = t/9, dyj = t - hh*9, dy = dyj/3, j = dyj - dy*3;
                const float* wp = wdw + (size_t)(cb+ci)*9 + j;
                float a = s_rw[hh*9 + dy]     * wp[0]
                        + s_rw[hh*9 + 3 + dy] * wp[3]
                        + s_rw[hh*9 + 6 + dy] * wp[6];
                s_A[ci*AST + t] = a;
            }
        }

        __syncthreads();   // BAR1: px/A visible

        // ---- gather + depthwise (registers) ----
        __bf16* dwp = s_dw[ck & 1];
        float d0[8], d1[8];
        #pragma unroll
        for (int i = 0; i < 8; i++) { d0[i] = 0.f; d1[i] = 0.f; }

        #pragma unroll
        for (int rr = 0; rr < 3; rr++) {
            int r = rl0 + rr;
            float cx[10];
            #pragma unroll
            for (int j = 0; j < 10; j++) {
                bf16x2 p = s_px[r*(PXW*64) + wi[j]];
                float lo = (float)p[0], hi = (float)p[1];
                cx[j] = fmaf(fx[j], hi - lo, lo);
            }
            {   // row hh0: dy = rr
                const float* Ab = &s_A[cl*AST + hh0*9 + rr*3];
                float A0 = Ab[0], A1 = Ab[1], A2 = Ab[2];
                #pragma unroll
                for (int i = 0; i < 8; i++)
                    d0[i] = fmaf(A0, cx[i], fmaf(A1, cx[i+1], fmaf(A2, cx[i+2], d0[i])));
            }
            int dyL = rr - dd;
            if ((unsigned)dyL <= 2u) {   // row hh0+1 (wave-uniform)
                const float* Ab = &s_A[cl*AST + (hh0+1)*9 + dyL*3];
                float A0 = Ab[0], A1 = Ab[1], A2 = Ab[2];
                #pragma unroll
                for (int i = 0; i < 8; i++)
                    d1[i] = fmaf(A0, cx[i], fmaf(A1, cx[i+1], fmaf(A2, cx[i+2], d1[i])));
            }
        }
        if (dd) {   // 4th row feeds only hh0+1 with dy=2 (wave-uniform)
            int r = rl0 + 3;
            float cx[10];
            #pragma unroll
            for (int j = 0; j < 10; j++) {
                bf16x2 p = s_px[r*(PXW*64) + wi[j]];
                float lo = (float)p[0], hi = (float)p[1];
                cx[j] = fmaf(fx[j], hi - lo, lo);
            }
            const float* Ab = &s_A[cl*AST + (hh0+1)*9 + 2*3];
            float A0 = Ab[0], A1 = Ab[1], A2 = Ab[2];
            #pragma unroll
            for (int i = 0; i < 8; i++)
                d1[i] = fmaf(A0, cx[i], fmaf(A1, cx[i+1], fmaf(A2, cx[i+2], d1[i])));
        }

        {   // write dw tile [px][cin_local]
            int pxb0 = (hh0*32 + wseg*8)*DWS + cl;
            int pxb1 = pxb0 + 32*DWS;
            #pragma unroll
            for (int i = 0; i < 8; i++) {
                dwp[pxb0 + i*DWS] = (__bf16)d0[i];
                dwp[pxb1 + i*DWS] = (__bf16)d1[i];
            }
        }

        // A-frags straight from global (L2-hot 64 KB); drained at BAR2
        const __bf16* wrow = wpwb + (size_t)(co + l16)*CIN + cb + quad*8;
        bf16x8 af00 = *(const bf16x8*)(wrow);
        bf16x8 af01 = *(const bf16x8*)(wrow + 32);
        bf16x8 af10 = *(const bf16x8*)(wrow + 16*CIN);
        bf16x8 af11 = *(const bf16x8*)(wrow + 16*CIN + 32);

        __syncthreads();   // BAR2: dw tile visible

        #pragma unroll
        for (int pt = 0; pt < 4; pt++) {
            const __bf16* bp = &dwp[(phx + pt*16 + l16)*DWS + quad*8];
            bf16x8 bf0 = *(const bf16x8*)(bp);
            bf16x8 bf1 = *(const bf16x8*)(bp + 32);
            acc[0][pt] = __builtin_amdgcn_mfma_f32_16x16x32_bf16(af00, bf0, acc[0][pt], 0,0,0);
            acc[0][pt] = __builtin_amdgcn_mfma_f32_16x16x32_bf16(af01, bf1, acc[0][pt], 0,0,0);
            acc[1][pt] = __builtin_amdgcn_mfma_f32_16x16x32_bf16(af10, bf0, acc[1][pt], 0,0,0);
            acc[1][pt] = __builtin_amdgcn_mfma_f32_16x16x32_bf16(af11, bf1, acc[1][pt], 0,0,0);
        }
        // no 3rd barrier: next chunk's staging touches s_px/s_A only (all
        // gathers done by BAR2); MFMA reads only s_dw[ck&1]; next dw writes
        // the other parity.
    }

    // ---- epilogue: fp32 out, 64B-contiguous per 16-lane group ----
    float* ob = out + ((size_t)b*COUT + co)*NPIX + (size_t)h0*UPW + w0;
    #pragma unroll
    for (int ot = 0; ot < 2; ot++)
        #pragma unroll
        for (int pt = 0; pt < 4; pt++) {
            int px = phx + pt*16 + l16;
            float* p = ob + (size_t)(ot*16 + quad*4)*NPIX + (px>>5)*UPW + (px&31);
            #pragma unroll
            for (int e = 0; e < 4; e++) p[(size_t)e*NPIX] = acc[ot][pt][e];
        }
}

extern "C" void kernel_launch(void* const* d_in, const int* in_sizes, int n_in,
                              void* d_out, int out_size, void* d_ws, size_t ws_size,
                              hipStream_t stream)
{
    const float* x   = (const float*)d_in[0];
    const float* wdw = (const float*)d_in[1];
    const float* wpw = (const float*)d_in[2];

    // d_ws: 64 KB bf16 copy of wpw (intermediate dwb eliminated entirely)
    wpw_cvt<<<dim3((COUT*CIN)/(256*8)), 256, 0, stream>>>(wpw, (__bf16*)d_ws);
    fused_kernel<<<dim3(UPW/32, UPH/4, 8), F_NT, 0, stream>>>(
        x, wdw, (const __bf16*)d_ws, (float*)d_out);
}

// Round 2
// 285.099 us; speedup vs baseline: 1.1351x; 1.1351x over previous
//
#include <hip/hip_runtime.h>

// Fully fused: out = wpw · depthwise3x3( bilinear_up(x) )
// Tile: 2 out-rows x 80 cols x 128 cout per block; 512 thr; K-chunks of 32 ch.
// Spill-safe (acc=40, grouped dw) + coalesced x staging + XCD-per-image swizzle.
#define CIN  256
#define HIN  60
#define WIN  80
#define UPH  120
#define UPW  160
#define COUT 128
#define NPIX (UPH*UPW)   // 19200

typedef __bf16 bf16x2 __attribute__((ext_vector_type(2)));
typedef __bf16 bf16x8 __attribute__((ext_vector_type(8)));
typedef float  floatx4 __attribute__((ext_vector_type(4)));

// ---------------- wpw fp32 -> bf16 [COUT][CIN] (runs once) ----------------
__global__ void wpw_cvt(const float* __restrict__ wpw, __bf16* __restrict__ wpwb)
{
    int i = (blockIdx.x * blockDim.x + threadIdx.x) * 8;
    float4 a = *(const float4*)(wpw + i);
    float4 b = *(const float4*)(wpw + i + 4);
    bf16x8 o = {(__bf16)a.x,(__bf16)a.y,(__bf16)a.z,(__bf16)a.w,
                (__bf16)b.x,(__bf16)b.y,(__bf16)b.z,(__bf16)b.w};
    *(bf16x8*)(wpwb + i) = o;
}

#define F_NT  512
#define KC    32             // cin per chunk
#define NCK   (CIN/KC)       // 8
#define PXR   4              // staged input rows (covers 2 out rows + interp)
#define PXQ   11             // staged float4-quads per row
#define PXC   (PXQ*4)        // 44 staged cols
#define NITEM (KC*PXR*PXQ)   // 1408 staging items per chunk

__global__ __launch_bounds__(F_NT, 4) void fused_kernel(
    const float* __restrict__ x,      // [8,256,60,80]
    const float* __restrict__ wdw,    // [256,1,3,3]
    const __bf16* __restrict__ wpwb,  // [128,256] bf16
    float* __restrict__ out)          // [8,128,120,160]
{
    // LDS: 45.1 + 20.5 + 2.4 KB = 68 KB -> 2 blocks/CU
    __shared__ __align__(16) bf16x2 s_px[2][PXR*PXC*KC];  // [r][c][ch^swz] pairs
    __shared__ __align__(16) __bf16 s_dw[2][160*KC];      // [px][ch^swz]
    __shared__ float s_A[KC*19];                          // [ch][hh*9+dy*3+j]
    __shared__ float s_rw[18];                            // [hh][i3][dy]

    const int tid = threadIdx.x;

    // ---- XCD-bijective swizzle: 960 blocks = 8 XCDs x 120; XCD k = image k ----
    const int bid = blockIdx.x;
    const int wg  = (bid & 7) * 120 + (bid >> 3);
    const int wt  = wg & 1;
    const int t2  = wg >> 1;           // 0..479
    const int ht  = t2 % 60;
    const int b   = t2 / 60;           // == XCD id

    const int h0 = ht * 2, w0 = wt * 80;
    const float HS = 59.0f / 121.0f, WS = 79.0f / 161.0f;
    const int rbase = (int)((float)h0 * HS);
    const int c0  = (int)((float)w0 * WS);
    const int c0a = c0 & ~3;           // aligned staged col base (0 or 36)

    // ---- block-invariant row-interp weights ----
    if (tid < 18) {
        int ahh = tid / 9, t = tid - ahh * 9;
        int i3 = t / 3, dy = t - i3 * 3;
        int ybh = (int)((float)(h0 + ahh) * HS);
        float hy = (float)(h0 + ahh + i3) * HS;
        int y0 = (int)hy; float fy = hy - (float)y0;
        int y1 = min(y0 + 1, HIN - 1);
        s_rw[tid] = ((y0 - ybh) == dy ? 1.f - fy : 0.f)
                  + ((y1 - ybh) == dy ? fy : 0.f);
    }

    // dw-producer decode: (ch, 10-px seg, out-row hh)
    const int ch  = tid & 31;
    const int seg = (tid >> 5) & 7;
    const int hh  = tid >> 8;                               // 0..1
    const int rbh = (int)((float)(h0 + hh) * HS) - rbase;   // 0 or 1

    // MFMA decode: wave = m-frag (16 cout rows), 10 n-frags (160 px)
    const int lane = tid & 63, wave = tid >> 6;
    const int quad = lane >> 4, l16 = lane & 15;
    const int dwrd_base = l16 * 64 + ((quad * 16) ^ ((l16 & 3) << 4));

    floatx4 acc[10];
    #pragma unroll
    for (int n = 0; n < 10; n++) acc[n] = (floatx4){0.f, 0.f, 0.f, 0.f};

    const float* xb = x + (size_t)b * CIN * (HIN * WIN);

    // ---- staging helpers (coalesced: lanes sweep quads of one (ch,row)) ----
    float4 xv[3]; float x5[3];
    auto loadx = [&](int cb) {
        #pragma unroll
        for (int k = 0; k < 3; k++) {
            int i = tid + k * F_NT;
            if (i < NITEM) {
                int q  = i % PXQ;
                int rc = i / PXQ;
                int r  = rc & 3;
                int c  = rc >> 2;                  // ch-local
                int gy = min(rbase + r, HIN - 1);
                const float* xrow = xb + (size_t)(cb + c) * (HIN * WIN)
                                  + gy * WIN + c0a;
                xv[k] = *(const float4*)(xrow + q * 4);
                x5[k] = xrow[min(q * 4 + 4, (WIN - 1) - c0a)];
            }
        }
    };
    auto storex = [&](int pbuf) {
        bf16x2* pxp = s_px[pbuf];
        #pragma unroll
        for (int k = 0; k < 3; k++) {
            int i = tid + k * F_NT;
            if (i < NITEM) {
                int q  = i % PXQ;
                int rc = i / PXQ;
                int r  = rc & 3;
                int c  = rc >> 2;
                float4 v = xv[k]; float x5v = x5[k];
                int ix = (r * PXC + q * 4) * KC + (c ^ q);   // XOR swizzle
                pxp[ix         ] = (bf16x2){(__bf16)v.x, (__bf16)v.y};
                pxp[ix +   KC  ] = (bf16x2){(__bf16)v.y, (__bf16)v.z};
                pxp[ix + 2*KC  ] = (bf16x2){(__bf16)v.z, (__bf16)v.w};
                pxp[ix + 3*KC  ] = (bf16x2){(__bf16)v.w, (__bf16)x5v};
            }
        }
    };

    loadx(0);
    __syncthreads();   // BAR0: s_rw visible

    for (int p = 0; p < NCK; p++) {
        const int cb = p * KC;

        // 1. write staged pairs (regs -> s_px[p&1])
        storex(p & 1);

        // 2. fold dw-kernel with row-interp -> s_A
        #pragma unroll
        for (int k = 0; k < 2; k++) {
            int i = tid + k * F_NT;
            if (i < KC * 18) {
                int ci = i / 18, t = i - ci * 18;
                int ahh = t / 9, dyj = t - ahh * 9;
                int dy = dyj / 3, j = dyj - dy * 3;
                const float* wp = wdw + (size_t)(cb + ci) * 9;
                float a = s_rw[ahh*9 + dy]     * wp[j]
                        + s_rw[ahh*9 + 3 + dy] * wp[3 + j]
                        + s_rw[ahh*9 + 6 + dy] * wp[6 + j];
                s_A[ci * 19 + t] = a;
            }
        }

        __syncthreads();   // BAR1: s_px[p&1] + s_A ready

        // 3. issue next chunk's global loads (in flight under gather+MFMA)
        if (p < NCK - 1) loadx(cb + KC);

        // 4. gather + depthwise (two 5-px register groups)
        float Ar[3][3];
        #pragma unroll
        for (int dy = 0; dy < 3; dy++)
            #pragma unroll
            for (int j = 0; j < 3; j++)
                Ar[dy][j] = s_A[ch * 19 + hh * 9 + dy * 3 + j];

        const bf16x2* pxp = s_px[p & 1];
        __bf16* dwp = s_dw[p & 1];
        #pragma unroll
        for (int g = 0; g < 2; g++) {
            const int ub = w0 + seg * 10 + g * 5;   // up-col base of group
            float fx[7]; int wj[7];
            #pragma unroll
            for (int j = 0; j < 7; j++) {
                float wx = (float)(ub + j) * WS;
                int x0 = (int)wx;
                fx[j] = wx - (float)x0;
                int c = x0 - c0a;
                wj[j] = c * KC + (ch ^ (c >> 2));
            }
            float d[5] = {0.f, 0.f, 0.f, 0.f, 0.f};
            #pragma unroll
            for (int dy = 0; dy < 3; dy++) {
                int r = rbh + dy;
                float cx[7];
                #pragma unroll
                for (int j = 0; j < 7; j++) {
                    bf16x2 pp = pxp[r * (PXC * KC) + wj[j]];
                    float lo = (float)pp[0], hi = (float)pp[1];
                    cx[j] = fmaf(fx[j], hi - lo, lo);
                }
                float A0 = Ar[dy][0], A1 = Ar[dy][1], A2 = Ar[dy][2];
                #pragma unroll
                for (int i = 0; i < 5; i++)
                    d[i] = fmaf(A0, cx[i],
                           fmaf(A1, cx[i+1],
                           fmaf(A2, cx[i+2], d[i])));
            }
            #pragma unroll
            for (int i = 0; i < 5; i++) {
                int px = hh * 80 + seg * 10 + g * 5 + i;
                dwp[px * KC + (ch ^ ((px & 3) << 3))] = (__bf16)d[i];
            }
        }

        // 5. A-frag from global (64 KB, L2-resident)
        bf16x8 af = *(const bf16x8*)(wpwb + (size_t)(wave * 16 + l16) * CIN
                                     + cb + quad * 8);

        __syncthreads();   // BAR2: dw tile ready

        // 6. MFMA: 10 frags, K=32
        const char* dwb = (const char*)s_dw[p & 1];
        #pragma unroll
        for (int n = 0; n < 10; n++) {
            bf16x8 bf = *(const bf16x8*)(dwb + dwrd_base + n * 1024);
            acc[n] = __builtin_amdgcn_mfma_f32_16x16x32_bf16(af, bf, acc[n], 0, 0, 0);
        }
    }

    // ---- epilogue: fp32 out ----
    float* ob = out + (size_t)(b * COUT + wave * 16 + quad * 4) * NPIX
              + (size_t)h0 * UPW + w0;
    #pragma unroll
    for (int n = 0; n < 10; n++) {
        int rowl = (n >= 5) ? 1 : 0;
        int col  = n * 16 + l16 - rowl * 80;
        float* pp = ob + (size_t)rowl * UPW + col;
        #pragma unroll
        for (int e = 0; e < 4; e++) pp[(size_t)e * NPIX] = acc[n][e];
    }
}

extern "C" void kernel_launch(void* const* d_in, const int* in_sizes, int n_in,
                              void* d_out, int out_size, void* d_ws, size_t ws_size,
                              hipStream_t stream)
{
    const float* x   = (const float*)d_in[0];
    const float* wdw = (const float*)d_in[1];
    const float* wpw = (const float*)d_in[2];

    wpw_cvt<<<dim3((COUT*CIN)/(256*8)), 256, 0, stream>>>(wpw, (__bf16*)d_ws);
    fused_kernel<<<dim3(960), F_NT, 0, stream>>>(
        x, wdw, (const __bf16*)d_ws, (float*)d_out);
}

// Round 3
// 246.970 us; speedup vs baseline: 1.3104x; 1.1544x over previous
//
#include <hip/hip_runtime.h>

// Fully fused: out = wpw · depthwise3x3( bilinear_up(x) )
// Tile: 2 out-rows x 80 cols x 128 cout per block; 512 thr; K-chunks of 32 ch.
// x staged via global_load_lds (async DMA, fp32, zero staging regs/VALU).
#define CIN  256
#define HIN  60
#define WIN  80
#define UPH  120
#define UPW  160
#define COUT 128
#define NPIX (UPH*UPW)   // 19200

typedef __bf16 bf16x8 __attribute__((ext_vector_type(8)));
typedef float  floatx4 __attribute__((ext_vector_type(4)));

// ---------------- wpw fp32 -> bf16 [COUT][CIN] (runs once) ----------------
__global__ void wpw_cvt(const float* __restrict__ wpw, __bf16* __restrict__ wpwb)
{
    int i = (blockIdx.x * blockDim.x + threadIdx.x) * 8;
    float4 a = *(const float4*)(wpw + i);
    float4 b = *(const float4*)(wpw + i + 4);
    bf16x8 o = {(__bf16)a.x,(__bf16)a.y,(__bf16)a.z,(__bf16)a.w,
                (__bf16)b.x,(__bf16)b.y,(__bf16)b.z,(__bf16)b.w};
    *(bf16x8*)(wpwb + i) = o;
}

#define F_NT  512
#define KC    32              // cin per chunk
#define NCK   (CIN/KC)        // 8
#define QPC   45              // 16B-quads per (ch): 4 rows x 11 quads + 1 pad
#define NIT   (KC*QPC)        // 1440 DMA items per chunk
#define NITP  1472            // padded to 23 waves (overflow-safe LDS size)

__global__ __launch_bounds__(F_NT, 4) void fused_kernel(
    const float* __restrict__ x,      // [8,256,60,80]
    const float* __restrict__ wdw,    // [256,1,3,3]
    const __bf16* __restrict__ wpwb,  // [128,256] bf16
    float* __restrict__ out)          // [8,128,120,160]
{
    // LDS 68.4 KB -> 2 blocks/CU
    __shared__ __align__(16) float  s_xf[2][NITP*4];   // 46.0 KB DMA-staged fp32
    __shared__ __align__(16) __bf16 s_dw[2][160*KC];   // 20.0 KB [px][ch^swz]
    __shared__ float s_A[KC*19];                       //  2.4 KB [ch][hh*9+dy*3+j]
    __shared__ float s_rw[18];                         // row-interp wgts [hh][i3][dy]

    const int tid = threadIdx.x;

    // ---- XCD-bijective swizzle: 960 = 8 XCDs x 120; XCD k = image k,
    //      j ascending -> resident set is a narrow row band (L2-resident) ----
    const int bid = blockIdx.x;
    const int wg  = (bid & 7) * 120 + (bid >> 3);
    const int wt  = wg & 1;
    const int t2  = wg >> 1;
    const int ht  = t2 % 60;
    const int b   = t2 / 60;

    const int h0 = ht * 2, w0 = wt * 80;
    const float HS = 59.0f / 121.0f, WS = 79.0f / 161.0f;
    const int rbase = (int)((float)h0 * HS);
    const int c0a = ((int)((float)w0 * WS)) & ~3;   // aligned staged col base

    // ---- block-invariant row-interp weights ----
    if (tid < 18) {
        int ahh = tid / 9, t = tid - ahh * 9;
        int i3 = t / 3, dy = t - i3 * 3;
        int ybh = (int)((float)(h0 + ahh) * HS);
        float hy = (float)(h0 + ahh + i3) * HS;
        int y0 = (int)hy; float fy = hy - (float)y0;
        int y1 = min(y0 + 1, HIN - 1);
        s_rw[tid] = ((y0 - ybh) == dy ? 1.f - fy : 0.f)
                  + ((y1 - ybh) == dy ? fy : 0.f);
    }

    const int lane = tid & 63, wave = tid >> 6;
    const int quad = lane >> 4, l16 = lane & 15;

    // dw-producer decode
    const int ch  = tid & 31;
    const int seg = (tid >> 5) & 7;
    const int hh  = tid >> 8;
    const int rbh = (int)((float)(h0 + hh) * HS) - rbase;   // 0 or 1

    // fold-producer decode (item A = tid, item B = tid+512 for tid<64)
    const int ciA = tid / 18, tA = tid - ciA * 18;
    const int hhA = tA / 9, dA = tA - hhA * 9, dyA = dA / 3, jA = dA - dyA * 3;
    const bool hasB = (tid < 64);
    const int iB = tid + 512, ciB = iB / 18, tB = iB - ciB * 18;
    const int hhB = tB / 9, dB = tB - hhB * 9, dyB = dB / 3, jB = dB - dyB * 3;

    const float* xb = x + (size_t)b * CIN * (HIN * WIN);

    // ---- async DMA: stage chunk cb's x into s_xf[buf] (fp32, linear) ----
    auto dma = [&](int cb, int buf) {
        #pragma unroll
        for (int k = 0; k < 3; k++) {
            int ws = (k * 8 + wave) * 64;          // wave-uniform item base
            if (ws < NIT) {
                int it = ws + lane;
                it = it < NIT ? it : NIT - 1;      // clamp overflow lanes' addr
                int c  = it / QPC;
                int t  = it - c * QPC;
                t = t < 44 ? t : 43;               // pad quad -> harmless addr
                int r = t / 11, q = t - r * 11;
                int gy = min(rbase + r, HIN - 1);
                const float* src = xb + (size_t)(cb + c) * (HIN * WIN)
                                 + gy * WIN + c0a + q * 4;
                __builtin_amdgcn_global_load_lds(
                    (const __attribute__((address_space(1))) void*)src,
                    (__attribute__((address_space(3))) void*)(&s_xf[buf][ws * 4]),
                    16, 0, 0);
            }
        }
    };

    float wA0, wA1, wA2, wB0 = 0.f, wB1 = 0.f, wB2 = 0.f;
    auto loadw = [&](int cb) {
        const float* wp = wdw + (size_t)(cb + ciA) * 9 + jA;
        wA0 = wp[0]; wA1 = wp[3]; wA2 = wp[6];
        if (hasB) {
            const float* wq = wdw + (size_t)(cb + ciB) * 9 + jB;
            wB0 = wq[0]; wB1 = wq[3]; wB2 = wq[6];
        }
    };

    floatx4 acc[10];
    #pragma unroll
    for (int n = 0; n < 10; n++) acc[n] = (floatx4){0.f, 0.f, 0.f, 0.f};

    // prologue: DMA chunk 0, wdw regs for chunk 0
    dma(0, 0);
    loadw(0);
    __syncthreads();   // BAR0: s_rw visible

    for (int p = 0; p < NCK; p++) {
        // 1. fold dw-kernel with row-interp -> s_A (from prefetched regs)
        s_A[ciA * 19 + tA] = s_rw[hhA*9 + dyA]     * wA0
                           + s_rw[hhA*9 + 3 + dyA] * wA1
                           + s_rw[hhA*9 + 6 + dyA] * wA2;
        if (hasB)
            s_A[ciB * 19 + tB] = s_rw[hhB*9 + dyB]     * wB0
                               + s_rw[hhB*9 + 3 + dyB] * wB1
                               + s_rw[hhB*9 + 6 + dyB] * wB2;

        asm volatile("s_waitcnt vmcnt(0)" ::: "memory");  // drain DMA(p)
        __syncthreads();   // BAR1: s_xf[p&1] + s_A ready

        // 2. issue next chunk's DMA + wdw prefetch (in flight under gather+MFMA)
        if (p < NCK - 1) {
            dma((p + 1) * KC, (p + 1) & 1);
            loadw((p + 1) * KC);
        }

        // 3. gather + depthwise from fp32 LDS (two 5-px groups)
        float Ar[3][3];
        #pragma unroll
        for (int dy = 0; dy < 3; dy++)
            #pragma unroll
            for (int j = 0; j < 3; j++)
                Ar[dy][j] = s_A[ch * 19 + hh * 9 + dy * 3 + j];

        const float* xfp = s_xf[p & 1];
        const int chb = ch * 180;
        __bf16* dwp = s_dw[p & 1];

        #pragma unroll
        for (int g = 0; g < 2; g++) {
            const int ub = w0 + seg * 10 + g * 5;
            float fx[7]; int ci[7];
            #pragma unroll
            for (int j = 0; j < 7; j++) {
                float wx = (float)(ub + j) * WS;
                int x0 = (int)wx;
                fx[j] = wx - (float)x0;
                ci[j] = chb + (x0 - c0a);
            }
            float d[5] = {0.f, 0.f, 0.f, 0.f, 0.f};
            #pragma unroll
            for (int dy = 0; dy < 3; dy++) {
                const float* rp = xfp + (rbh + dy) * 44;
                float cx[7];
                #pragma unroll
                for (int j = 0; j < 7; j++) {
                    float lo = rp[ci[j]], hi = rp[ci[j] + 1];
                    cx[j] = fmaf(fx[j], hi - lo, lo);
                }
                float A0 = Ar[dy][0], A1 = Ar[dy][1], A2 = Ar[dy][2];
                #pragma unroll
                for (int i = 0; i < 5; i++)
                    d[i] = fmaf(A0, cx[i],
                           fmaf(A1, cx[i+1],
                           fmaf(A2, cx[i+2], d[i])));
            }
            #pragma unroll
            for (int i = 0; i < 5; i++) {
                int px = hh * 80 + seg * 10 + g * 5 + i;
                dwp[px * KC + (ch ^ ((px & 3) << 3))] = (__bf16)d[i];
            }
        }

        // 4. A-frag from global (64 KB, L2-resident)
        bf16x8 af = *(const bf16x8*)(wpwb + (size_t)(wave * 16 + l16) * CIN
                                     + p * KC + quad * 8);

        __syncthreads();   // BAR2: s_dw[p&1] ready

        // 5. MFMA: 10 n-frags, K=32
        const char* dwb = (const char*)dwp;
        const int dwrd_base = l16 * 64 + ((quad * 16) ^ ((l16 & 3) << 4));
        #pragma unroll
        for (int n = 0; n < 10; n++) {
            bf16x8 bf = *(const bf16x8*)(dwb + dwrd_base + n * 1024);
            acc[n] = __builtin_amdgcn_mfma_f32_16x16x32_bf16(af, bf, acc[n], 0, 0, 0);
        }
    }

    // ---- epilogue: fp32 out, nontemporal (no write-allocate) ----
    float* ob = out + (size_t)(b * COUT + wave * 16 + quad * 4) * NPIX
              + (size_t)h0 * UPW + w0;
    #pragma unroll
    for (int n = 0; n < 10; n++) {
        int rowl = (n >= 5) ? 1 : 0;
        int col  = n * 16 + l16 - rowl * 80;
        float* pp = ob + (size_t)rowl * UPW + col;
        #pragma unroll
        for (int e = 0; e < 4; e++)
            __builtin_nontemporal_store(acc[n][e], pp + (size_t)e * NPIX);
    }
}

extern "C" void kernel_launch(void* const* d_in, const int* in_sizes, int n_in,
                              void* d_out, int out_size, void* d_ws, size_t ws_size,
                              hipStream_t stream)
{
    const float* x   = (const float*)d_in[0];
    const float* wdw = (const float*)d_in[1];
    const float* wpw = (const float*)d_in[2];

    wpw_cvt<<<dim3((COUT*CIN)/(256*8)), 256, 0, stream>>>(wpw, (__bf16*)d_ws);
    fused_kernel<<<dim3(960), F_NT, 0, stream>>>(
        x, wdw, (const __bf16*)d_ws, (float*)d_out);
}